// Round 17
// baseline (306.250 us; speedup 1.0000x reference)
//
#include <hip/hip_runtime.h>
#include <hip/hip_bf16.h>
#include <stdint.h>

typedef __attribute__((ext_vector_type(8))) short bf16x8;
typedef __attribute__((ext_vector_type(4))) float f32x4;
typedef __attribute__((ext_vector_type(16))) float f32x16;

#define S_LEN 2048
#define D_DIM 128
#define HQ_N  32
#define NT32  64            // 32-row kv subtiles per kv-head
#define SUB_B 8192          // 32-row subtile bytes
#define UNITS_PER_HEAD 160  // sum over j of ceil((j+1)/16)
#define N_UNITS 5120        // 32 heads x 160
#define PO_OFF  (8u * 1024 * 1024)                  // after 8MB KV ws
#define ML_OFF  (PO_OFF + (size_t)N_UNITS * 8192)   // after partial O

__device__ __forceinline__ ushort f2bf(float f) {
  union { float f; uint32_t u; } c; c.f = f;
  uint32_t u = c.u;
  u += 0x7FFFu + ((u >> 16) & 1u);
  return (ushort)(u >> 16);
}

__device__ __forceinline__ uint32_t cvtpk(float lo, float hi) {
  uint32_t r;
  asm("v_cvt_pk_bf16_f32 %0, %1, %2" : "=v"(r) : "v"(lo), "v"(hi));
  return r;
}

// cross-half (lane^32) max via permlane32_swap (validated R9-R16)
__device__ __forceinline__ float xhalf_max(float x) {
  uint32_t a = __builtin_bit_cast(uint32_t, x), b;
  asm volatile("v_mov_b32 %0, %1" : "=&v"(b) : "v"(a));
  asm volatile("v_permlane32_swap_b32 %0, %1" : "+v"(a), "+v"(b));
  return fmaxf(__builtin_bit_cast(float, a), __builtin_bit_cast(float, b));
}

// slots before q-tile j within a head (chunk counts 1/2/3/4 per 16-j band)
__device__ __forceinline__ int pfx(int j) {
  if (j < 16) return j;
  if (j < 32) return 16 + 2 * (j - 16);
  if (j < 48) return 48 + 3 * (j - 32);
  return 96 + 4 * (j - 48);
}

// ---- prep K: fragment-ordered bf16 subtiles (layout unchanged R7-R16) ----
__global__ __launch_bounds__(256) void prep_k(const float* __restrict__ K,
                                              ushort* __restrict__ KT) {
  int tid  = blockIdx.x * 256 + threadIdx.x;
  int tile = tid >> 9;
  int c    = tid & 511;
  int s    = c >> 6;
  int lane = c & 63;
  int l31  = lane & 31, hi = lane >> 5;
  const float* src = K + ((size_t)(tile * 32 + l31)) * D_DIM + 16 * s + 8 * hi;
  float4 x = *(const float4*)src;
  float4 y = *(const float4*)(src + 4);
  union { ushort u[8]; bf16x8 v; } o;
  o.u[0] = f2bf(x.x); o.u[1] = f2bf(x.y); o.u[2] = f2bf(x.z); o.u[3] = f2bf(x.w);
  o.u[4] = f2bf(y.x); o.u[5] = f2bf(y.y); o.u[6] = f2bf(y.z); o.u[7] = f2bf(y.w);
  *(bf16x8*)(KT + (size_t)tid * 8) = o.v;
}

// ---- prep V: fragment-ordered transposed subtiles (unchanged R7-R16) ----
__global__ __launch_bounds__(256) void prep_v(const float* __restrict__ V,
                                              ushort* __restrict__ VT) {
  int tid  = blockIdx.x * 256 + threadIdx.x;
  int tile = tid >> 9;
  int cc   = tid & 511;
  int l31  = cc & 31;
  int hi   = (cc >> 5) & 1;
  int c    = (cc >> 6) & 1;
  int dt   = cc >> 7;
  int hkv  = tile >> 6, ktv = tile & 63;
  const float* src = V + ((size_t)hkv * S_LEN + ktv * 32 + 16 * c + 8 * hi) * D_DIM
                       + 32 * dt + l31;
  union { ushort u[8]; bf16x8 v; } o;
  #pragma unroll
  for (int jj = 0; jj < 8; ++jj) o.u[jj] = f2bf(src[(size_t)jj * D_DIM]);
  *(bf16x8*)(VT + (size_t)tid * 8) = o.v;
}

// ---- split-KV flash attention: 5120 uniform 1-wave units ----
__global__ __launch_bounds__(64, 4) void attn_part(
    const float* __restrict__ Q, const ushort* __restrict__ KT,
    const ushort* __restrict__ VT, char* __restrict__ PO,
    float* __restrict__ ML) {
  const int id = blockIdx.x;             // 0..5119
  const int g  = id & 7;                 // kv-head == XCD affinity
  const int qh = (id >> 3) & 3;
  const int h  = g * 4 + qh;
  const int v  = 159 - (id >> 5);        // reversed: longest units dispatch first
  int j, ch;
  if (v < 16)      { j = v;              ch = 0; }
  else if (v < 48) { int w = v - 16; j = 16 + (w >> 1); ch = w & 1; }
  else if (v < 96) { int w = v - 48; int q3 = w / 3; j = 32 + q3; ch = w - 3 * q3; }
  else             { int w = v - 96; j = 48 + (w >> 2); ch = w & 3; }
  const int kt0 = ch * 16;
  const int kt1 = min(kt0 + 16, j + 1);  // tiles [kt0, kt1), 32 kv rows each

  const int lane = threadIdx.x;
  const int l31  = lane & 31;
  const int hi   = lane >> 5;
  const int qrow = j * 32 + l31;

  const char* kt_base = (const char*)KT + (size_t)g * NT32 * SUB_B;
  const char* vt_base = (const char*)VT + (size_t)g * NT32 * SUB_B;

  // Q fragments (B operand), log2-domain scale
  const float scale = 0.08838834764831845f * 1.4426950408889634f;
  bf16x8 qf[8];
  {
    const float* qp = Q + ((size_t)h * S_LEN + qrow) * D_DIM;
    #pragma unroll
    for (int s = 0; s < 8; ++s) {
      const float* px = qp + 16 * s + 8 * hi;
      float4 x = *(const float4*)px;
      float4 y = *(const float4*)(px + 4);
      bf16x8 f;
      f[0] = (short)f2bf(x.x * scale); f[1] = (short)f2bf(x.y * scale);
      f[2] = (short)f2bf(x.z * scale); f[3] = (short)f2bf(x.w * scale);
      f[4] = (short)f2bf(y.x * scale); f[5] = (short)f2bf(y.y * scale);
      f[6] = (short)f2bf(y.z * scale); f[7] = (short)f2bf(y.w * scale);
      qf[s] = f;
    }
  }

  bf16x8 ones;
  #pragma unroll
  for (int s = 0; s < 8; ++s) ones[s] = (short)0x3F80;
  const f32x16 zero16 = {};

  f32x16 o4[4] = {};       // O^T: q=l31, d = 32*dt + (r&3)+8*(r>>2)+4*hi
  float mrow = -1e30f, lsum = 0.f;

  for (int kt = kt0; kt < kt1; ++kt) {
    const char* kp = kt_base + (size_t)kt * SUB_B;
    const char* vp = vt_base + (size_t)kt * SUB_B;

    bf16x8 kf[8], vf[8];
    #pragma unroll
    for (int s = 0; s < 8; ++s)
      kf[s] = *(const bf16x8*)(kp + (s * 64 + lane) * 16);
    #pragma unroll
    for (int u = 0; u < 8; ++u)
      vf[u] = *(const bf16x8*)(vp + (u * 64 + lane) * 16);

    // ---- S^T = K Q ----
    f32x16 st = {};
    __builtin_amdgcn_s_setprio(1);
    #pragma unroll
    for (int s = 0; s < 8; ++s)
      st = __builtin_amdgcn_mfma_f32_32x32x16_bf16(kf[s], qf[s], st, 0, 0, 0);
    __builtin_amdgcn_s_setprio(0);

    // ---- causal mask (diagonal tile only) ----
    if (kt == j) {
      #pragma unroll
      for (int r = 0; r < 16; ++r) {
        int kv = 32 * kt + (r & 3) + 8 * (r >> 2) + 4 * hi;
        if (kv > qrow) st[r] = -1e30f;
      }
    }

    // ---- online softmax (validated R9) ----
    float t8[8];
    #pragma unroll
    for (int e = 0; e < 8; ++e) t8[e] = fmaxf(st[e], st[e + 8]);
    float mx = fmaxf(fmaxf(fmaxf(t8[0], t8[1]), fmaxf(t8[2], t8[3])),
                     fmaxf(fmaxf(t8[4], t8[5]), fmaxf(t8[6], t8[7])));
    mx = xhalf_max(mx);
    if (!__all(mx <= mrow + 8.0f)) {     // defer-max (T13)
      float mnew = fmaxf(mrow, mx);
      float alpha = exp2f(mrow - mnew);
      #pragma unroll
      for (int dt = 0; dt < 4; ++dt) o4[dt] *= alpha;
      lsum *= alpha;
      mrow = mnew;
    }
    #pragma unroll
    for (int e = 0; e < 16; ++e) st[e] = exp2f(st[e] - mrow);

    // ---- pack P^T (validated recipe) ----
    bf16x8 pb[2];
    #pragma unroll
    for (int c = 0; c < 2; ++c) {
      const int r0 = c * 8;
      uint32_t a0 = cvtpk(st[r0 + 0], st[r0 + 1]);
      uint32_t b0 = cvtpk(st[r0 + 4], st[r0 + 5]);
      asm volatile("v_permlane32_swap_b32 %0, %1" : "+v"(a0), "+v"(b0));
      uint32_t a1 = cvtpk(st[r0 + 2], st[r0 + 3]);
      uint32_t b1 = cvtpk(st[r0 + 6], st[r0 + 7]);
      asm volatile("v_permlane32_swap_b32 %0, %1" : "+v"(a1), "+v"(b1));
      union { uint32_t u[4]; bf16x8 v; } pu;
      pu.u[0] = a0; pu.u[1] = a1; pu.u[2] = b0; pu.u[3] = b1;
      pb[c] = pu.v;
    }

    // ---- row-sum via ones-MFMA + PV ----
    f32x16 pbsum = __builtin_amdgcn_mfma_f32_32x32x16_bf16(ones, pb[0], zero16, 0, 0, 0);
    pbsum = __builtin_amdgcn_mfma_f32_32x32x16_bf16(ones, pb[1], pbsum, 0, 0, 0);
    __builtin_amdgcn_s_setprio(1);
    #pragma unroll
    for (int dt = 0; dt < 4; ++dt) {
      o4[dt] = __builtin_amdgcn_mfma_f32_32x32x16_bf16(vf[2 * dt + 0], pb[0], o4[dt], 0, 0, 0);
      o4[dt] = __builtin_amdgcn_mfma_f32_32x32x16_bf16(vf[2 * dt + 1], pb[1], o4[dt], 0, 0, 0);
    }
    __builtin_amdgcn_s_setprio(0);
    lsum += pbsum[0];
  }

  // ---- epilogue: write UNNORMALIZED partial (bf16 O + f32 m,l) ----
  const int slot = h * UNITS_PER_HEAD + pfx(j) + ch;
  char* po = PO + (size_t)slot * 8192 + l31 * 256;
  #pragma unroll
  for (int dt = 0; dt < 4; ++dt)
    #pragma unroll
    for (int rq = 0; rq < 4; ++rq) {
      uint32_t u0 = cvtpk(o4[dt][rq * 4 + 0], o4[dt][rq * 4 + 1]);
      uint32_t u1 = cvtpk(o4[dt][rq * 4 + 2], o4[dt][rq * 4 + 3]);
      uint2 uu = {u0, u1};
      *(uint2*)(po + (32 * dt + 8 * rq + 4 * hi) * 2) = uu;
    }
  if (hi == 0) {
    float2 mlv = {mrow, lsum};
    *(float2*)(ML + (size_t)slot * 64 + l31 * 2) = mlv;
  }
}

// ---- combine: LSE-merge up to 4 partials per (h, j), write final O ----
__global__ __launch_bounds__(128) void comb(const char* __restrict__ PO,
                                            const float* __restrict__ ML,
                                            float* __restrict__ O) {
  const int b = blockIdx.x;              // h*64 + j
  const int h = b >> 6, j = b & 63;
  const int k = 1 + (j >> 4);
  const int base = h * UNITS_PER_HEAD + pfx(j);
  const int d = threadIdx.x;             // 0..127

  __shared__ float sm[4][32][2];
  if (threadIdx.x < 32) {
    for (int c = 0; c < k; ++c) {
      float2 v = *(const float2*)(ML + (size_t)(base + c) * 64 + threadIdx.x * 2);
      sm[c][threadIdx.x][0] = v.x;
      sm[c][threadIdx.x][1] = v.y;
    }
  }
  __syncthreads();

  for (int q = 0; q < 32; ++q) {
    float M = -1e30f;
    for (int c = 0; c < k; ++c) M = fmaxf(M, sm[c][q][0]);
    float L = 0.f, acc = 0.f;
    for (int c = 0; c < k; ++c) {
      float wgt = exp2f(sm[c][q][0] - M);
      L += sm[c][q][1] * wgt;
      ushort pv = *(const ushort*)(PO + (size_t)(base + c) * 8192 + q * 256 + d * 2);
      uint32_t fu = ((uint32_t)pv) << 16;
      acc += wgt * __builtin_bit_cast(float, fu);
    }
    O[((size_t)h * S_LEN + j * 32 + q) * D_DIM + d] = acc / L;
  }
}

extern "C" void kernel_launch(void* const* d_in, const int* in_sizes, int n_in,
                              void* d_out, int out_size, void* d_ws, size_t ws_size,
                              hipStream_t stream) {
  const float* Q = (const float*)d_in[0];
  const float* K = (const float*)d_in[1];
  const float* V = (const float*)d_in[2];
  float* O = (float*)d_out;
  ushort* wsK = (ushort*)d_ws;
  ushort* wsV = wsK + (size_t)8 * NT32 * (SUB_B / 2);       // +4MB
  char*   PO  = (char*)d_ws + PO_OFF;                       // 40MB partial O (bf16)
  float*  ML  = (float*)((char*)d_ws + ML_OFF);             // 1.3MB m,l
  prep_k<<<1024, 256, 0, stream>>>(K, wsK);
  prep_v<<<1024, 256, 0, stream>>>(V, wsV);
  attn_part<<<N_UNITS, 64, 0, stream>>>(Q, wsK, wsV, PO, ML);
  comb<<<HQ_N * 64, 128, 0, stream>>>(PO, ML, O);
}

// Round 18
// 128.662 us; speedup vs baseline: 2.3803x; 2.3803x over previous
//
#include <hip/hip_runtime.h>
#include <hip/hip_bf16.h>
#include <stdint.h>

typedef __attribute__((ext_vector_type(8))) short bf16x8;
typedef __attribute__((ext_vector_type(4))) float f32x4;
typedef __attribute__((ext_vector_type(16))) float f32x16;

#define S_LEN 2048
#define D_DIM 128
#define HQ_N  32
#define NT32  64            // 32-row kv subtiles per kv-head
#define SUB_B 8192          // 32-row subtile bytes
#define UNITS_PER_HEAD 160  // sum over j of ceil((j+1)/16)
#define N_UNITS 5120        // 32 heads x 160
#define PO_OFF  (8u * 1024 * 1024)                  // after 8MB KV ws
#define ML_OFF  (PO_OFF + (size_t)N_UNITS * 8192)   // after partial O

__device__ __forceinline__ ushort f2bf(float f) {
  union { float f; uint32_t u; } c; c.f = f;
  uint32_t u = c.u;
  u += 0x7FFFu + ((u >> 16) & 1u);
  return (ushort)(u >> 16);
}

__device__ __forceinline__ uint32_t cvtpk(float lo, float hi) {
  uint32_t r;
  asm("v_cvt_pk_bf16_f32 %0, %1, %2" : "=v"(r) : "v"(lo), "v"(hi));
  return r;
}

// cross-half (lane^32) max via permlane32_swap (validated R9-R17)
__device__ __forceinline__ float xhalf_max(float x) {
  uint32_t a = __builtin_bit_cast(uint32_t, x), b;
  asm volatile("v_mov_b32 %0, %1" : "=&v"(b) : "v"(a));
  asm volatile("v_permlane32_swap_b32 %0, %1" : "+v"(a), "+v"(b));
  return fmaxf(__builtin_bit_cast(float, a), __builtin_bit_cast(float, b));
}

// slots before q-tile j within a head (chunk counts 1/2/3/4 per 16-j band)
__device__ __forceinline__ int pfx(int j) {
  if (j < 16) return j;
  if (j < 32) return 16 + 2 * (j - 16);
  if (j < 48) return 48 + 3 * (j - 32);
  return 96 + 4 * (j - 48);
}

// ---- prep K: fragment-ordered bf16 subtiles (layout unchanged R7-R17) ----
__global__ __launch_bounds__(256) void prep_k(const float* __restrict__ K,
                                              ushort* __restrict__ KT) {
  int tid  = blockIdx.x * 256 + threadIdx.x;
  int tile = tid >> 9;
  int c    = tid & 511;
  int s    = c >> 6;
  int lane = c & 63;
  int l31  = lane & 31, hi = lane >> 5;
  const float* src = K + ((size_t)(tile * 32 + l31)) * D_DIM + 16 * s + 8 * hi;
  float4 x = *(const float4*)src;
  float4 y = *(const float4*)(src + 4);
  union { ushort u[8]; bf16x8 v; } o;
  o.u[0] = f2bf(x.x); o.u[1] = f2bf(x.y); o.u[2] = f2bf(x.z); o.u[3] = f2bf(x.w);
  o.u[4] = f2bf(y.x); o.u[5] = f2bf(y.y); o.u[6] = f2bf(y.z); o.u[7] = f2bf(y.w);
  *(bf16x8*)(KT + (size_t)tid * 8) = o.v;
}

// ---- prep V: fragment-ordered transposed subtiles (unchanged R7-R17) ----
__global__ __launch_bounds__(256) void prep_v(const float* __restrict__ V,
                                              ushort* __restrict__ VT) {
  int tid  = blockIdx.x * 256 + threadIdx.x;
  int tile = tid >> 9;
  int cc   = tid & 511;
  int l31  = cc & 31;
  int hi   = (cc >> 5) & 1;
  int c    = (cc >> 6) & 1;
  int dt   = cc >> 7;
  int hkv  = tile >> 6, ktv = tile & 63;
  const float* src = V + ((size_t)hkv * S_LEN + ktv * 32 + 16 * c + 8 * hi) * D_DIM
                       + 32 * dt + l31;
  union { ushort u[8]; bf16x8 v; } o;
  #pragma unroll
  for (int jj = 0; jj < 8; ++jj) o.u[jj] = f2bf(src[(size_t)jj * D_DIM]);
  *(bf16x8*)(VT + (size_t)tid * 8) = o.v;
}

// ---- split-KV flash attention: 5120 uniform 1-wave units ----
// R17 BUG FIX: launch_bounds (64,2) not (64,4) — the min-waves=4 clamp forced
// VGPR=64 and ~1GB of scratch spill (FETCH 490MB). (64,2) -> ~116 VGPR, no spill.
__global__ __launch_bounds__(64, 2) void attn_part(
    const float* __restrict__ Q, const ushort* __restrict__ KT,
    const ushort* __restrict__ VT, char* __restrict__ PO,
    float* __restrict__ ML) {
  const int id = blockIdx.x;             // 0..5119
  const int g  = id & 7;                 // kv-head == XCD affinity
  const int qh = (id >> 3) & 3;
  const int h  = g * 4 + qh;
  const int v  = 159 - (id >> 5);        // reversed: longest units dispatch first
  int j, ch;
  if (v < 16)      { j = v;              ch = 0; }
  else if (v < 48) { int w = v - 16; j = 16 + (w >> 1); ch = w & 1; }
  else if (v < 96) { int w = v - 48; int q3 = w / 3; j = 32 + q3; ch = w - 3 * q3; }
  else             { int w = v - 96; j = 48 + (w >> 2); ch = w & 3; }
  const int kt0 = ch * 16;
  const int kt1 = min(kt0 + 16, j + 1);  // tiles [kt0, kt1), 32 kv rows each

  const int lane = threadIdx.x;
  const int l31  = lane & 31;
  const int hi   = lane >> 5;
  const int qrow = j * 32 + l31;

  const char* kt_base = (const char*)KT + (size_t)g * NT32 * SUB_B;
  const char* vt_base = (const char*)VT + (size_t)g * NT32 * SUB_B;

  // Q fragments (B operand), log2-domain scale
  const float scale = 0.08838834764831845f * 1.4426950408889634f;
  bf16x8 qf[8];
  {
    const float* qp = Q + ((size_t)h * S_LEN + qrow) * D_DIM;
    #pragma unroll
    for (int s = 0; s < 8; ++s) {
      const float* px = qp + 16 * s + 8 * hi;
      float4 x = *(const float4*)px;
      float4 y = *(const float4*)(px + 4);
      bf16x8 f;
      f[0] = (short)f2bf(x.x * scale); f[1] = (short)f2bf(x.y * scale);
      f[2] = (short)f2bf(x.z * scale); f[3] = (short)f2bf(x.w * scale);
      f[4] = (short)f2bf(y.x * scale); f[5] = (short)f2bf(y.y * scale);
      f[6] = (short)f2bf(y.z * scale); f[7] = (short)f2bf(y.w * scale);
      qf[s] = f;
    }
  }

  bf16x8 ones;
  #pragma unroll
  for (int s = 0; s < 8; ++s) ones[s] = (short)0x3F80;
  const f32x16 zero16 = {};

  f32x16 o4[4] = {};       // O^T: q=l31, d = 32*dt + (r&3)+8*(r>>2)+4*hi
  float mrow = -1e30f, lsum = 0.f;

  for (int kt = kt0; kt < kt1; ++kt) {
    const char* kp = kt_base + (size_t)kt * SUB_B;
    const char* vp = vt_base + (size_t)kt * SUB_B;

    bf16x8 kf[8], vf[8];
    #pragma unroll
    for (int s = 0; s < 8; ++s)
      kf[s] = *(const bf16x8*)(kp + (s * 64 + lane) * 16);
    #pragma unroll
    for (int u = 0; u < 8; ++u)
      vf[u] = *(const bf16x8*)(vp + (u * 64 + lane) * 16);

    // ---- S^T = K Q ----
    f32x16 st = {};
    __builtin_amdgcn_s_setprio(1);
    #pragma unroll
    for (int s = 0; s < 8; ++s)
      st = __builtin_amdgcn_mfma_f32_32x32x16_bf16(kf[s], qf[s], st, 0, 0, 0);
    __builtin_amdgcn_s_setprio(0);

    // ---- causal mask (diagonal tile only) ----
    if (kt == j) {
      #pragma unroll
      for (int r = 0; r < 16; ++r) {
        int kv = 32 * kt + (r & 3) + 8 * (r >> 2) + 4 * hi;
        if (kv > qrow) st[r] = -1e30f;
      }
    }

    // ---- online softmax (validated R9) ----
    float t8[8];
    #pragma unroll
    for (int e = 0; e < 8; ++e) t8[e] = fmaxf(st[e], st[e + 8]);
    float mx = fmaxf(fmaxf(fmaxf(t8[0], t8[1]), fmaxf(t8[2], t8[3])),
                     fmaxf(fmaxf(t8[4], t8[5]), fmaxf(t8[6], t8[7])));
    mx = xhalf_max(mx);
    if (!__all(mx <= mrow + 8.0f)) {     // defer-max (T13)
      float mnew = fmaxf(mrow, mx);
      float alpha = exp2f(mrow - mnew);
      #pragma unroll
      for (int dt = 0; dt < 4; ++dt) o4[dt] *= alpha;
      lsum *= alpha;
      mrow = mnew;
    }
    #pragma unroll
    for (int e = 0; e < 16; ++e) st[e] = exp2f(st[e] - mrow);

    // ---- pack P^T (validated recipe) ----
    bf16x8 pb[2];
    #pragma unroll
    for (int c = 0; c < 2; ++c) {
      const int r0 = c * 8;
      uint32_t a0 = cvtpk(st[r0 + 0], st[r0 + 1]);
      uint32_t b0 = cvtpk(st[r0 + 4], st[r0 + 5]);
      asm volatile("v_permlane32_swap_b32 %0, %1" : "+v"(a0), "+v"(b0));
      uint32_t a1 = cvtpk(st[r0 + 2], st[r0 + 3]);
      uint32_t b1 = cvtpk(st[r0 + 6], st[r0 + 7]);
      asm volatile("v_permlane32_swap_b32 %0, %1" : "+v"(a1), "+v"(b1));
      union { uint32_t u[4]; bf16x8 v; } pu;
      pu.u[0] = a0; pu.u[1] = a1; pu.u[2] = b0; pu.u[3] = b1;
      pb[c] = pu.v;
    }

    // ---- row-sum via ones-MFMA + PV ----
    f32x16 pbsum = __builtin_amdgcn_mfma_f32_32x32x16_bf16(ones, pb[0], zero16, 0, 0, 0);
    pbsum = __builtin_amdgcn_mfma_f32_32x32x16_bf16(ones, pb[1], pbsum, 0, 0, 0);
    __builtin_amdgcn_s_setprio(1);
    #pragma unroll
    for (int dt = 0; dt < 4; ++dt) {
      o4[dt] = __builtin_amdgcn_mfma_f32_32x32x16_bf16(vf[2 * dt + 0], pb[0], o4[dt], 0, 0, 0);
      o4[dt] = __builtin_amdgcn_mfma_f32_32x32x16_bf16(vf[2 * dt + 1], pb[1], o4[dt], 0, 0, 0);
    }
    __builtin_amdgcn_s_setprio(0);
    lsum += pbsum[0];
  }

  // ---- epilogue: write UNNORMALIZED partial (bf16 O + f32 m,l) ----
  const int slot = h * UNITS_PER_HEAD + pfx(j) + ch;
  char* po = PO + (size_t)slot * 8192 + l31 * 256;
  #pragma unroll
  for (int dt = 0; dt < 4; ++dt)
    #pragma unroll
    for (int rq = 0; rq < 4; ++rq) {
      uint32_t u0 = cvtpk(o4[dt][rq * 4 + 0], o4[dt][rq * 4 + 1]);
      uint32_t u1 = cvtpk(o4[dt][rq * 4 + 2], o4[dt][rq * 4 + 3]);
      uint2 uu = {u0, u1};
      *(uint2*)(po + (32 * dt + 8 * rq + 4 * hi) * 2) = uu;
    }
  if (hi == 0) {
    float2 mlv = {mrow, lsum};
    *(float2*)(ML + (size_t)slot * 64 + l31 * 2) = mlv;
  }
}

// ---- combine: LSE-merge up to 4 partials per (h, j), write final O ----
__global__ __launch_bounds__(128) void comb(const char* __restrict__ PO,
                                            const float* __restrict__ ML,
                                            float* __restrict__ O) {
  const int b = blockIdx.x;              // h*64 + j
  const int h = b >> 6, j = b & 63;
  const int k = 1 + (j >> 4);
  const int base = h * UNITS_PER_HEAD + pfx(j);
  const int d = threadIdx.x;             // 0..127

  __shared__ float sm[4][32][2];
  if (threadIdx.x < 32) {
    for (int c = 0; c < k; ++c) {
      float2 v = *(const float2*)(ML + (size_t)(base + c) * 64 + threadIdx.x * 2);
      sm[c][threadIdx.x][0] = v.x;
      sm[c][threadIdx.x][1] = v.y;
    }
  }
  __syncthreads();

  for (int q = 0; q < 32; ++q) {
    float M = -1e30f;
    for (int c = 0; c < k; ++c) M = fmaxf(M, sm[c][q][0]);
    float L = 0.f, acc = 0.f;
    for (int c = 0; c < k; ++c) {
      float wgt = exp2f(sm[c][q][0] - M);
      L += sm[c][q][1] * wgt;
      ushort pv = *(const ushort*)(PO + (size_t)(base + c) * 8192 + q * 256 + d * 2);
      uint32_t fu = ((uint32_t)pv) << 16;
      acc += wgt * __builtin_bit_cast(float, fu);
    }
    O[((size_t)h * S_LEN + j * 32 + q) * D_DIM + d] = acc / L;
  }
}

extern "C" void kernel_launch(void* const* d_in, const int* in_sizes, int n_in,
                              void* d_out, int out_size, void* d_ws, size_t ws_size,
                              hipStream_t stream) {
  const float* Q = (const float*)d_in[0];
  const float* K = (const float*)d_in[1];
  const float* V = (const float*)d_in[2];
  float* O = (float*)d_out;
  ushort* wsK = (ushort*)d_ws;
  ushort* wsV = wsK + (size_t)8 * NT32 * (SUB_B / 2);       // +4MB
  char*   PO  = (char*)d_ws + PO_OFF;                       // 40MB partial O (bf16)
  float*  ML  = (float*)((char*)d_ws + ML_OFF);             // 1.3MB m,l
  prep_k<<<1024, 256, 0, stream>>>(K, wsK);
  prep_v<<<1024, 256, 0, stream>>>(V, wsV);
  attn_part<<<N_UNITS, 64, 0, stream>>>(Q, wsK, wsV, PO, ML);
  comb<<<HQ_N * 64, 128, 0, stream>>>(PO, ML, O);
}